// Round 1
// baseline (216.370 us; speedup 1.0000x reference)
//
#include <hip/hip_runtime.h>
#include <hip/hip_bf16.h>

typedef short s16x8 __attribute__((ext_vector_type(8)));
typedef float f32x16 __attribute__((ext_vector_type(16)));

namespace {
constexpr int kB = 16;
constexpr int kD = 256;
constexpr int kHW = 16384;
constexpr int kM = 4096;
constexpr int kN = kB * kM;             // 65536 samples
constexpr int kKChunk = 1024;
constexpr int kNChunks = kN / kKChunk;  // 64
constexpr float kLam = 0.005f;
}

// ---------------------------------------------------------------------------
// Kernel 1: per-(input, b, d) plane gather + partial stats.
// One block loads a full 64KB (b,d) plane into LDS (coalesced float4),
// gathers the 4096 sampled pixels, writes bf16 into [feature][sample]
// layout, and reduces sum / sumsq for the normalization statistics.
// ---------------------------------------------------------------------------
__global__ __launch_bounds__(256) void gather_stats_kernel(
    const float* __restrict__ z, const float* __restrict__ zp,
    const int* __restrict__ flat_idx,
    __hip_bfloat16* __restrict__ Ag, __hip_bfloat16* __restrict__ Bg,
    float* __restrict__ Sp, float* __restrict__ SSp)
{
    __shared__ float plane[kHW];   // exactly 64 KiB
    const int bx = blockIdx.x;
    const int sel = bx >> 12;               // 0: z, 1: z_prime
    const int b = (bx >> 8) & (kB - 1);
    const int d = bx & (kD - 1);
    const int t = threadIdx.x;

    const float* src = (sel ? zp : z) + ((size_t)(b * kD + d)) * kHW;
    const float4* s4 = (const float4*)src;
    float4* p4 = (float4*)plane;
#pragma unroll
    for (int i = 0; i < 16; ++i) p4[t + i * 256] = s4[t + i * 256];
    __syncthreads();

    const int* bi = flat_idx + b * kM;
    __hip_bfloat16* dst = (sel ? Bg : Ag) + (size_t)d * kN + b * kM;
    float s = 0.f, ss = 0.f;
#pragma unroll
    for (int i = 0; i < 16; ++i) {
        const int m = t + i * 256;
        const float v = plane[bi[m]];
        s += v;
        ss += v * v;
        dst[m] = __float2bfloat16(v);   // coalesced 2B writes, m contiguous
    }
    // wave reduce, then cross-wave via (now dead) plane buffer
#pragma unroll
    for (int o = 32; o; o >>= 1) {
        s += __shfl_down(s, o);
        ss += __shfl_down(ss, o);
    }
    __syncthreads();                    // everyone done reading plane
    if ((t & 63) == 0) {
        plane[t >> 6] = s;
        plane[4 + (t >> 6)] = ss;
    }
    __syncthreads();
    if (t == 0) {
        const int slot = (sel * kB + b) * kD + d;
        Sp[slot]  = plane[0] + plane[1] + plane[2] + plane[3];
        SSp[slot] = plane[4] + plane[5] + plane[6] + plane[7];
    }
}

// ---------------------------------------------------------------------------
// Kernel 2: partial Gram GEMM.  G = A * B^T where A, B are [D][N] bf16
// (feature-major).  Grid = 16 C-tiles (64x64) x 64 K-chunks (1024).
// Block = 4 waves (2x2 of 32x32 MFMA tiles).  Deterministic partials to ws.
// ---------------------------------------------------------------------------
__global__ __launch_bounds__(256) void gemm_part_kernel(
    const __hip_bfloat16* __restrict__ Ag, const __hip_bfloat16* __restrict__ Bg,
    float* __restrict__ partial)
{
    const int bx = blockIdx.x;
    const int tile = bx & 15;
    const int chunk = bx >> 4;
    const int tr = (tile >> 2) * 64;
    const int tc = (tile & 3) * 64;
    const int tid = threadIdx.x;
    const int wid = tid >> 6;
    const int lane = tid & 63;
    const int l31 = lane & 31;
    const int half = lane >> 5;
    const int d0 = tr + (wid >> 1) * 32;
    const int e0 = tc + (wid & 1) * 32;

    const __hip_bfloat16* arow = Ag + (size_t)(d0 + l31) * kN;
    const __hip_bfloat16* brow = Bg + (size_t)(e0 + l31) * kN;
    int kb = chunk * kKChunk + half * 8;

    f32x16 acc;
#pragma unroll
    for (int i = 0; i < 16; ++i) acc[i] = 0.f;

#pragma unroll 4
    for (int it = 0; it < kKChunk / 16; ++it) {
        // A-operand 32x32x16: lane l holds A[l&31][(l>>5)*8 + j], j=0..7
        s16x8 a = *(const s16x8*)(arow + kb);
        // B-operand: lane l holds B[(l>>5)*8 + j][l&31]; with Bg feature-major
        // this is the same contiguous 16B load.
        s16x8 bf = *(const s16x8*)(brow + kb);
        acc = __builtin_amdgcn_mfma_f32_32x32x16_bf16(a, bf, acc, 0, 0, 0);
        kb += 16;
    }

    float* out = partial + (size_t)chunk * (kD * kD);
#pragma unroll
    for (int r = 0; r < 16; ++r) {
        // C/D layout (verified m74/m101): col = lane&31, row = (r&3)+8*(r>>2)+4*(lane>>5)
        const int row = (r & 3) + 8 * (r >> 2) + 4 * half;
        out[(d0 + row) * kD + (e0 + l31)] = acc[r];
    }
}

// ---------------------------------------------------------------------------
// Kernel 3: reduce K-chunk partials -> G (256x256 f32)
// ---------------------------------------------------------------------------
__global__ __launch_bounds__(256) void reduce_gram_kernel(
    const float* __restrict__ partial, float* __restrict__ G)
{
    const int d = blockIdx.x;
    const int e = threadIdx.x;
    float s = 0.f;
#pragma unroll 8
    for (int c = 0; c < kNChunks; ++c)
        s += partial[(size_t)c * (kD * kD) + d * kD + e];
    G[d * kD + e] = s;
}

// ---------------------------------------------------------------------------
// Kernel 4: final loss.  Single block.
// C_de = (G_de/N - mu_d nu_e) / (sd_d sd_e);  loss = sum((1-diag)^2) + lam*sum(off^2)
// ---------------------------------------------------------------------------
__global__ __launch_bounds__(256) void loss_kernel(
    const float* __restrict__ G, const float* __restrict__ Sp,
    const float* __restrict__ SSp, float* __restrict__ out)
{
    __shared__ float muA[kD], isA[kD], muB[kD], isB[kD];
    const int t = threadIdx.x;
    float sA = 0.f, ssA = 0.f, sB = 0.f, ssB = 0.f;
#pragma unroll
    for (int b = 0; b < kB; ++b) {
        sA  += Sp [(0 * kB + b) * kD + t];
        ssA += SSp[(0 * kB + b) * kD + t];
        sB  += Sp [(1 * kB + b) * kD + t];
        ssB += SSp[(1 * kB + b) * kD + t];
    }
    const float n = (float)kN;
    const float mA = sA / n, mB = sB / n;
    float vA = (ssA - n * mA * mA) / (n - 1.f);
    float vB = (ssB - n * mB * mB) / (n - 1.f);
    float sdA = fmaxf(sqrtf(fmaxf(vA, 0.f)), 1e-6f);
    float sdB = fmaxf(sqrtf(fmaxf(vB, 0.f)), 1e-6f);
    muA[t] = mA; isA[t] = 1.f / sdA;
    muB[t] = mB; isB[t] = 1.f / sdB;
    __syncthreads();

    float acc = 0.f;
    for (int d = 0; d < kD; ++d) {
        const int e = t;
        const float c = (G[d * kD + e] / n - muA[d] * muB[e]) * isA[d] * isB[e];
        if (d == e) { const float u = 1.f - c; acc += u * u; }
        else        { acc += kLam * c * c; }
    }
#pragma unroll
    for (int o = 32; o; o >>= 1) acc += __shfl_down(acc, o);
    __shared__ float r[4];
    if ((t & 63) == 0) r[t >> 6] = acc;
    __syncthreads();
    if (t == 0) out[0] = r[0] + r[1] + r[2] + r[3];
}

// ---------------------------------------------------------------------------
extern "C" void kernel_launch(void* const* d_in, const int* in_sizes, int n_in,
                              void* d_out, int out_size, void* d_ws, size_t ws_size,
                              hipStream_t stream) {
    const float* z  = (const float*)d_in[0];
    const float* zp = (const float*)d_in[1];
    const int* flat_idx = (const int*)d_in[2];
    float* out = (float*)d_out;

    char* ws = (char*)d_ws;
    // ws layout:
    //   [0,   32MB)  Ag  bf16 [256][65536]
    //   [32,  64MB)  Bg  bf16 [256][65536]
    //   [64,  80MB)  partial f32 [64][256][256]
    //   [80MB, +32K) Sp  f32 [2][16][256]
    //   ..   +32K    SSp
    //   ..   +256K   G   f32 [256][256]
    __hip_bfloat16* Ag = (__hip_bfloat16*)ws;
    __hip_bfloat16* Bg = (__hip_bfloat16*)(ws + (size_t)32 * 1024 * 1024);
    float* partial = (float*)(ws + (size_t)64 * 1024 * 1024);
    float* Sp  = (float*)(ws + (size_t)80 * 1024 * 1024);
    float* SSp = Sp + 2 * kB * kD;
    float* G   = (float*)(ws + (size_t)80 * 1024 * 1024 + 64 * 1024);

    gather_stats_kernel<<<2 * kB * kD, 256, 0, stream>>>(z, zp, flat_idx, Ag, Bg, Sp, SSp);
    gemm_part_kernel<<<16 * kNChunks, 256, 0, stream>>>(Ag, Bg, partial);
    reduce_gram_kernel<<<kD, 256, 0, stream>>>(partial, G);
    loss_kernel<<<1, 256, 0, stream>>>(G, Sp, SSp, out);
}